// Round 3
// baseline (288.944 us; speedup 1.0000x reference)
//
#include <hip/hip_runtime.h>

// Problem constants (fixed by reference)
#define TT 2048
#define BB 16384
#define NSTEP 18431      // TT + BB - 1
#define HOR 24
#define MM 24            // seasonality period

// Chunked-speculation parameters
#define PCH 64           // parallel chunks (one wave, lane = chunk)
#define CLEN 288         // steps per chunk; PCH*CLEN = 18432 = NSTEP+1; multiple of 24
#define WARM 1440        // warm-up steps = 60*24; slow-mode residual ~0.919^60 ~ 6e-3

// Workspace layout (floats)
#define SEG 20480        // per-array segment (multiple of 4; > NSTEP+MM)
// ws+0      : ts[SEG]      input series (padded with 1.0f)
// ws+SEG    : xn[SEG]      normalized outputs (lambda-invariant)
// ws+2*SEG  : larr[SEG]    level per step (chunk-scaled, fixed by fix_kernel)
// ws+3*SEG  : Sarr[SEG]    S_t (index t; [0,24) = init, S_{t+24} written at step t)
// ws+4*SEG  : mwarm[PCH]   sum_j log2(s_j) at end of warm-up (time cstart)
// ws+4*SEG+PCH : mend[PCH] sum_j log2(s_j) at end of main (time cend)

#define FILLA_BLOCKS 32768            // (BB*TT/4)/256
#define FILLB_BLOCKS 1536             // (BB*HOR)/256

__device__ __forceinline__ float frcp(float x) {        // ~0.5 ulp
    float r = __builtin_amdgcn_rcpf(x);
    return r * fmaf(-x, r, 2.0f);
}
__device__ __forceinline__ float frcp_fast(float x) {   // raw v_rcp_f32, ~1 ulp
    return __builtin_amdgcn_rcpf(x);
}

__global__ void __launch_bounds__(256) prep_kernel(const float* __restrict__ x,
                                                   const float* __restrict__ init_seas,
                                                   float* __restrict__ ws) {
    int tid = blockIdx.x * blockDim.x + threadIdx.x;
    float* ts   = ws;
    float* Sarr = ws + 3 * SEG;
    if (tid < SEG) {
        float v;
        if (tid < TT)          v = x[tid];                                      // x[0, t, 0]
        else if (tid < NSTEP)  v = x[(size_t)(tid - (TT - 1)) * TT + (TT - 1)]; // x[b, T-1, 0]
        else                   v = 1.0f;                                        // pad (never read back)
        ts[tid] = v;
    }
    if (tid < MM) Sarr[tid] = init_seas[tid];
}

__global__ void __launch_bounds__(64, 1) scan_kernel(const float* __restrict__ alpha,
                                                     const float* __restrict__ gamma,
                                                     const float* __restrict__ init_seas,
                                                     const float* __restrict__ level,
                                                     float* __restrict__ ws) {
    const int i = threadIdx.x;                 // chunk id, one lane per chunk
    const float* ts = ws;
    float* xn    = ws + SEG;
    float* larr  = ws + 2 * SEG;
    float* Sarr  = ws + 3 * SEG;
    float* mwarm = ws + 4 * SEG;
    float* mend  = ws + 4 * SEG + PCH;

    const float a  = alpha[0];
    const float g  = gamma[0];
    const float oa = 1.0f - a;
    const float og = 1.0f - g;

    float l = level[0];
    float s[MM];
#pragma unroll
    for (int j = 0; j < MM; ++j) s[j] = init_seas[j];   // guess; chunks with cstart<=WARM are exact

    const int cstart = i * CLEN;
    int t = cstart - WARM;
    if (t < 0) t = 0;

    // ---- warm-up (no stores): contracts all non-neutral modes (slowest ~0.919/cycle) ----
    for (; t < cstart; t += MM) {
        float yv[MM];
#pragma unroll
        for (int q = 0; q < MM / 4; ++q) {
            const float4 v = *(const float4*)(ts + t + 4 * q);
            yv[4*q+0] = v.x; yv[4*q+1] = v.y; yv[4*q+2] = v.z; yv[4*q+3] = v.w;
        }
#pragma unroll
        for (int j = 0; j < MM; ++j) {
            const float y  = yv[j];
            const float u  = y * frcp_fast(s[j]);        // y / S_t (raw rcp: error contracts)
            l = fmaf(oa, l, a * u);                      // level update
            s[j] = fmaf(og, s[j], g * y * frcp_fast(l)); // S_{t+24}
        }
    }
    // Geometric-mean handoff signature: sum_j log2 s_j at time cstart.
    // Non-neutral eigenmodes have s-part ~ omega^j with sum_j omega^j = 0 ->
    // first-order contamination cancels; only the neutral (lambda) offset survives.
    {
        float m = 0.0f;
#pragma unroll
        for (int j = 0; j < MM; ++j) m += __log2f(s[j]);
        mwarm[i] = m;
    }

    // ---- main chunk (store xn, l, S) ----
    const int cend = cstart + CLEN;
    for (; t < cend; t += MM) {
        float yv[MM], xv[MM], lv[MM], sv[MM];
#pragma unroll
        for (int q = 0; q < MM / 4; ++q) {
            const float4 v = *(const float4*)(ts + t + 4 * q);
            yv[4*q+0] = v.x; yv[4*q+1] = v.y; yv[4*q+2] = v.z; yv[4*q+3] = v.w;
        }
#pragma unroll
        for (int j = 0; j < MM; ++j) {
            const float y  = yv[j];
            const float u  = y * frcp(s[j]);
            l = fmaf(oa, l, a * u);
            const float rl = frcp(l);
            s[j] = fmaf(og, s[j], g * y * rl);
            xv[j] = u * rl;                           // y / (S_t * l_t)  (lambda-invariant)
            lv[j] = l;
            sv[j] = s[j];
        }
#pragma unroll
        for (int q = 0; q < MM / 4; ++q) {
            *(float4*)(xn   + t + 4 * q)      = make_float4(xv[4*q], xv[4*q+1], xv[4*q+2], xv[4*q+3]);
            *(float4*)(larr + t + 4 * q)      = make_float4(lv[4*q], lv[4*q+1], lv[4*q+2], lv[4*q+3]);
            *(float4*)(Sarr + MM + t + 4 * q) = make_float4(sv[4*q], sv[4*q+1], sv[4*q+2], sv[4*q+3]);
        }
    }
    // signature at time cend (same time point as chunk i+1's mwarm)
    {
        float m = 0.0f;
#pragma unroll
        for (int j = 0; j < MM; ++j) m += __log2f(s[j]);
        mend[i] = m;
    }
}

__global__ void __launch_bounds__(256) fix_kernel(float* __restrict__ ws) {
    float* larr  = ws + 2 * SEG;
    float* Sarr  = ws + 3 * SEG;
    float* mwarm = ws + 4 * SEG;
    float* mend  = ws + 4 * SEG + PCH;
    __shared__ float lam[PCH], ilam[PCH];

    if (threadIdx.x == 0) {
        // l~ = lam_c * l_true ; s~ = s_true / lam_c
        // mwarm[c]   = Mtrue(t_c) - 24*log2(lam_c)
        // mend[c-1]  = Mtrue(t_c) - 24*log2(lam_{c-1})
        // => log2(lam_c/lam_{c-1}) = (mend[c-1] - mwarm[c]) / 24
        float ll = 0.0f;
        lam[0] = 1.0f; ilam[0] = 1.0f;
        for (int c = 1; c < PCH; ++c) {
            ll += (mend[c - 1] - mwarm[c]) * (1.0f / 24.0f);
            lam[c]  = exp2f(ll);
            ilam[c] = exp2f(-ll);
        }
    }
    __syncthreads();

    const int NT = PCH * CLEN;   // 18432
    for (int t = threadIdx.x; t < NT; t += blockDim.x)
        larr[t] *= ilam[t / CLEN];           // true l = l~ / lam
    for (int t = threadIdx.x; t < NT; t += blockDim.x)
        Sarr[MM + t] *= lam[t / CLEN];       // true S = S~ * lam  (S_{t+24} written at step t)
}

__global__ void __launch_bounds__(256) fill_kernel(const float* __restrict__ ws,
                                                   float* __restrict__ out) {
    const float* xn   = ws + SEG;
    const float* larr = ws + 2 * SEG;
    const float* Sarr = ws + 3 * SEG;
    const int bid = blockIdx.x;

    if (bid < FILLA_BLOCKS) {
        // x_out[b, t] = xn[b + t] ; one float4 of t per thread
        const int q  = bid * 256 + threadIdx.x;      // [0, BB*TT/4)
        const int b  = q >> 9;                       // / (TT/4)
        const int t0 = (q & 511) << 2;
        const int src = b + t0;
        const float4 v = make_float4(xn[src], xn[src + 1], xn[src + 2], xn[src + 3]);
        *(float4*)(out + ((size_t)b * TT + t0)) = v;
    } else {
        // denorm[b, h, 0] = l[2047+b] ; denorm[b, h, 1] = S[2048+b+h]
        const int r = (bid - FILLA_BLOCKS) * 256 + threadIdx.x;  // [0, BB*HOR)
        const int b = r / HOR;
        const int h = r - b * HOR;
        const float lev = larr[(TT - 1) + b];
        const float se  = Sarr[TT + b + h];
        *(float2*)(out + (size_t)BB * TT + 2 * (size_t)r) = make_float2(lev, se);
    }
}

extern "C" void kernel_launch(void* const* d_in, const int* in_sizes, int n_in,
                              void* d_out, int out_size, void* d_ws, size_t ws_size,
                              hipStream_t stream) {
    const float* x     = (const float*)d_in[0];
    const float* alpha = (const float*)d_in[1];
    const float* gamma = (const float*)d_in[2];
    const float* iseas = (const float*)d_in[3];
    const float* level = (const float*)d_in[4];
    float* ws  = (float*)d_ws;
    float* out = (float*)d_out;

    prep_kernel<<<SEG / 256, 256, 0, stream>>>(x, iseas, ws);
    scan_kernel<<<1, PCH, 0, stream>>>(alpha, gamma, iseas, level, ws);
    fix_kernel<<<1, 256, 0, stream>>>(ws);
    fill_kernel<<<FILLA_BLOCKS + FILLB_BLOCKS, 256, 0, stream>>>(ws, out);
}

// Round 4
// 248.856 us; speedup vs baseline: 1.1611x; 1.1611x over previous
//
#include <hip/hip_runtime.h>

// Problem constants (fixed by reference)
#define TT 2048
#define BB 16384
#define NSTEP 18431      // TT + BB - 1
#define HOR 24
#define MM 24            // seasonality period

// Chunked-speculation parameters
#define PCH 128          // parallel chunks (2 waves, lane = chunk)
#define CLEN 144         // steps per chunk; PCH*CLEN = 18432 = NSTEP+1; multiple of 24
#define WARM 1248        // warm-up steps = 52*24; slow-mode residual ~0.919^52 (~2x R3's, 3x margin)

// Workspace layout (floats)
#define SEG 20480        // per-array segment (multiple of 4; > NSTEP+MM)
// ws+0        : ts[SEG]    input series (padded with 1.0f)
// ws+SEG      : xn[SEG]    normalized outputs (lambda-invariant)
// ws+2*SEG    : larr[SEG]  level per step (chunk-frame; corrected on the fly in fill)
// ws+3*SEG    : Sarr[SEG]  S_t (index t; [0,24) = init, S_{t+24} written at step t)
// ws+4*SEG    : lamg[PCH]  per-chunk lambda
// ws+4*SEG+PCH: ilamg[PCH] per-chunk 1/lambda

#define FILLA_BLOCKS 32768            // (BB*TT/4)/256
#define FILLB_BLOCKS 1536             // (BB*HOR)/256

typedef float f4v __attribute__((ext_vector_type(4)));

__device__ __forceinline__ float frcp(float x) {        // ~0.5 ulp
    float r = __builtin_amdgcn_rcpf(x);
    return r * fmaf(-x, r, 2.0f);
}
__device__ __forceinline__ float frcp_fast(float x) {   // raw v_rcp_f32, ~1 ulp
    return __builtin_amdgcn_rcpf(x);
}

__global__ void __launch_bounds__(256) prep_kernel(const float* __restrict__ x,
                                                   const float* __restrict__ init_seas,
                                                   float* __restrict__ ws) {
    int tid = blockIdx.x * blockDim.x + threadIdx.x;
    float* ts   = ws;
    float* Sarr = ws + 3 * SEG;
    if (tid < SEG) {
        float v;
        if (tid < TT)          v = x[tid];                                      // x[0, t, 0]
        else if (tid < NSTEP)  v = x[(size_t)(tid - (TT - 1)) * TT + (TT - 1)]; // x[b, T-1, 0]
        else                   v = 1.0f;                                        // pad (never read back)
        ts[tid] = v;
    }
    if (tid < MM) Sarr[tid] = init_seas[tid];
}

__global__ void __launch_bounds__(PCH, 1) scan_kernel(const float* __restrict__ alpha,
                                                      const float* __restrict__ gamma,
                                                      const float* __restrict__ init_seas,
                                                      const float* __restrict__ level,
                                                      float* __restrict__ ws) {
    const int i = threadIdx.x;                 // chunk id, one lane per chunk
    const float* ts = ws;
    float* xn    = ws + SEG;
    float* larr  = ws + 2 * SEG;
    float* Sarr  = ws + 3 * SEG;
    float* lamg  = ws + 4 * SEG;
    float* ilamg = ws + 4 * SEG + PCH;

    __shared__ float sm_warm[PCH], sm_end[PCH], sm_ll[PCH];

    const float a  = alpha[0];
    const float g  = gamma[0];
    const float oa = 1.0f - a;
    const float og = 1.0f - g;

    float l = level[0];
    float s[MM];
#pragma unroll
    for (int j = 0; j < MM; ++j) s[j] = init_seas[j];   // guess; chunks with cstart<=WARM are exact

    const int cstart = i * CLEN;
    int t = cstart - WARM;
    if (t < 0) t = 0;

    // ---- warm-up (no stores): contracts all non-neutral modes (slowest ~0.919/cycle) ----
    for (; t < cstart; t += MM) {
        float yv[MM];
#pragma unroll
        for (int q = 0; q < MM / 4; ++q) {
            const float4 v = *(const float4*)(ts + t + 4 * q);
            yv[4*q+0] = v.x; yv[4*q+1] = v.y; yv[4*q+2] = v.z; yv[4*q+3] = v.w;
        }
#pragma unroll
        for (int j = 0; j < MM; ++j) {
            const float y  = yv[j];
            const float u  = y * frcp_fast(s[j]);        // y / S_t (raw rcp: error contracts)
            l = fmaf(oa, l, a * u);                      // level update
            s[j] = fmaf(og, s[j], g * y * frcp_fast(l)); // S_{t+24}
        }
    }
    // Geometric-mean handoff signature: sum_j log2 s_j at time cstart.
    // Non-neutral eigenmodes have s-part ~ omega^j with sum_j omega^j = 0 ->
    // first-order contamination cancels; only the neutral (lambda) offset survives.
    {
        float m = 0.0f;
#pragma unroll
        for (int j = 0; j < MM; ++j) m += __log2f(s[j]);
        sm_warm[i] = m;
    }

    // ---- main chunk (store xn, l, S) ----
    const int cend = cstart + CLEN;
    for (; t < cend; t += MM) {
        float yv[MM], xv[MM], lv[MM], sv[MM];
#pragma unroll
        for (int q = 0; q < MM / 4; ++q) {
            const float4 v = *(const float4*)(ts + t + 4 * q);
            yv[4*q+0] = v.x; yv[4*q+1] = v.y; yv[4*q+2] = v.z; yv[4*q+3] = v.w;
        }
#pragma unroll
        for (int j = 0; j < MM; ++j) {
            const float y  = yv[j];
            const float u  = y * frcp(s[j]);
            l = fmaf(oa, l, a * u);
            const float rl = frcp(l);
            s[j] = fmaf(og, s[j], g * y * rl);
            xv[j] = u * rl;                           // y / (S_t * l_t)  (lambda-invariant)
            lv[j] = l;
            sv[j] = s[j];
        }
#pragma unroll
        for (int q = 0; q < MM / 4; ++q) {
            *(float4*)(xn   + t + 4 * q)      = make_float4(xv[4*q], xv[4*q+1], xv[4*q+2], xv[4*q+3]);
            *(float4*)(larr + t + 4 * q)      = make_float4(lv[4*q], lv[4*q+1], lv[4*q+2], lv[4*q+3]);
            *(float4*)(Sarr + MM + t + 4 * q) = make_float4(sv[4*q], sv[4*q+1], sv[4*q+2], sv[4*q+3]);
        }
    }
    // signature at time cend (same time point as chunk i+1's sm_warm)
    {
        float m = 0.0f;
#pragma unroll
        for (int j = 0; j < MM; ++j) m += __log2f(s[j]);
        sm_end[i] = m;
    }
    __syncthreads();

    // ---- lambda chain, in-kernel (replaces fix_kernel) ----
    // l~ = lam_c * l_true ; s~ = s_true / lam_c
    // log2(lam_c/lam_{c-1}) = (mend[c-1] - mwarm[c]) / 24 ; prefix-sum over c.
    float d = (i == 0) ? 0.0f : (sm_end[i - 1] - sm_warm[i]) * (1.0f / 24.0f);
    sm_ll[i] = d;
    __syncthreads();
#pragma unroll
    for (int off = 1; off < PCH; off <<= 1) {
        float add = (i >= off) ? sm_ll[i - off] : 0.0f;
        __syncthreads();
        sm_ll[i] += add;
        __syncthreads();
    }
    const float ll = sm_ll[i];
    lamg[i]  = exp2f(ll);
    ilamg[i] = exp2f(-ll);
}

__global__ void __launch_bounds__(256) fill_kernel(const float* __restrict__ ws,
                                                   float* __restrict__ out) {
    const float* xn    = ws + SEG;
    const float* larr  = ws + 2 * SEG;
    const float* Sarr  = ws + 3 * SEG;
    const float* lamg  = ws + 4 * SEG;
    const float* ilamg = ws + 4 * SEG + PCH;
    const int bid = blockIdx.x;

    if (bid < FILLA_BLOCKS) {
        // x_out[b, t] = xn[b + t] ; one float4 of t per thread; streaming nt store
        const int q  = bid * 256 + threadIdx.x;      // [0, BB*TT/4)
        const int b  = q >> 9;                       // / (TT/4)
        const int t0 = (q & 511) << 2;
        const int src = b + t0;
        f4v v;
        v.x = xn[src]; v.y = xn[src + 1]; v.z = xn[src + 2]; v.w = xn[src + 3];
        __builtin_nontemporal_store(v, (f4v*)(out + ((size_t)b * TT + t0)));
    } else {
        // denorm[b, h, 0] = l[2047+b]*ilam ; denorm[b, h, 1] = S[2048+b+h]*lam
        __shared__ float slam[PCH], silam[PCH];
        if (threadIdx.x < PCH) {
            slam[threadIdx.x]  = lamg[threadIdx.x];
            silam[threadIdx.x] = ilamg[threadIdx.x];
        }
        __syncthreads();
        const int r = (bid - FILLA_BLOCKS) * 256 + threadIdx.x;  // [0, BB*HOR)
        const int b = r / HOR;
        const int h = r - b * HOR;
        const int tl = (TT - 1) + b;                 // larr time index
        const int tsx = TT + b + h;                  // Sarr array index (written at step tsx-MM)
        const float lev = larr[tl]  * silam[tl / CLEN];
        const float se  = Sarr[tsx] * slam[(tsx - MM) / CLEN];
        *(float2*)(out + (size_t)BB * TT + 2 * (size_t)r) = make_float2(lev, se);
    }
}

extern "C" void kernel_launch(void* const* d_in, const int* in_sizes, int n_in,
                              void* d_out, int out_size, void* d_ws, size_t ws_size,
                              hipStream_t stream) {
    const float* x     = (const float*)d_in[0];
    const float* alpha = (const float*)d_in[1];
    const float* gamma = (const float*)d_in[2];
    const float* iseas = (const float*)d_in[3];
    const float* level = (const float*)d_in[4];
    float* ws  = (float*)d_ws;
    float* out = (float*)d_out;

    prep_kernel<<<SEG / 256, 256, 0, stream>>>(x, iseas, ws);
    scan_kernel<<<1, PCH, 0, stream>>>(alpha, gamma, iseas, level, ws);
    fill_kernel<<<FILLA_BLOCKS + FILLB_BLOCKS, 256, 0, stream>>>(ws, out);
}